// Round 14
// baseline (148.375 us; speedup 1.0000x reference)
//
#include <hip/hip_runtime.h>
#include <math.h>

// Fully-fused single-pass pipeline + XCD swizzle + 3 blocks/CU.
// r13 confirmed the XCD-affinity swizzle (FETCH 76->10.2 MB, 65.5 us). The
// remaining stall (VALUBusy 35%, Occ 19%) is LDS latency + ~22 barriers
// unhidden at 2 blocks/CU. LDS fits 3 blocks (3x54272=162816<=163840); the
// register budget at launch_bounds(256,3) is ~168 total/wave and the true
// peak live set (~125-145: acc 40 + retained modes 16 + windows/temps; Fr/Fi
// dead in the last band) should fit -- unlike r3/r4/r6 whose stash demanded
// 220+. Single change from passing r13 for clean attribution; if WRITE_SIZE
// blows up (spill) revert to (256,2).

#define NTH 256
#define PHYS(i) ((i) + ((i) >> 4))

typedef _Float16 f16x2 __attribute__((ext_vector_type(2)));

__device__ __forceinline__ void rset(f16x2* r, int j, float v) {
  if (j & 1) r[j >> 1].y = (_Float16)v;
  else       r[j >> 1].x = (_Float16)v;
}
__device__ __forceinline__ float rget(const f16x2* r, int j) {
  return (j & 1) ? (float)r[j >> 1].y : (float)r[j >> 1].x;
}

// accumulate 5 band energies + upper-triangular products into acc[20]
__device__ __forceinline__ void madd5(float* acc, float m0, float m1, float m2,
                                      float m3, float m4) {
  float e[5];
  e[0] = m0 * m0; e[1] = m1 * m1; e[2] = m2 * m2; e[3] = m3 * m3; e[4] = m4 * m4;
  int id = 5;
#pragma unroll
  for (int a = 0; a < 5; ++a) {
    acc[a] += e[a];
#pragma unroll
    for (int l = a; l < 5; ++l) { acc[id] += e[a] * e[l]; ++id; }
  }
}

// ---------------- tables setup (16 blocks) ----------------
__device__ __forceinline__ float mask_f32(int k, int j) {
  // replicate reference: freqs=fftfreq(4096).astype(f32), centers f32, /0.2f, expf
  float f = (float)((j < 2048) ? j : (j - 4096)) * (1.0f / 4096.0f);
  float c = ((float)k - 2.5f) / 5.0f;
  float df = fabsf(f - c);
  float q = df / 0.2f;
  return expf(-0.5f * (q * q));
}

__global__ void setup_k(float2* __restrict__ Wt, float* __restrict__ Mdr) {
  int j = blockIdx.x * NTH + threadIdx.x;   // 0..4095
  double ang = -(2.0 * 3.14159265358979323846 / 4096.0) * (double)j;
  double s, c;
  sincos(ang, &s, &c);
  Wt[j] = make_float2((float)c, (float)s);
  int jr = (int)(__brev((unsigned)j) >> 20);            // bitrev12
  int jrn = (4096 - jr) & 4095;
#pragma unroll
  for (int k = 0; k < 3; ++k) {   // bands 0,1,2; 3,4 via Nyquist correction
    float m1 = mask_f32(k, jr);
    float m2 = mask_f32(k, jrn);
    Mdr[k * 4096 + j] = (float)(((double)m1 + (double)m2) * (0.5 / 4096.0));
  }
}

// ---------------- FFT building blocks (f32) ----------------
template <int S, bool INV>
__device__ __forceinline__ void fft_stage(float* __restrict__ SRe, float* __restrict__ SIm,
                                          const float2* __restrict__ Wt, int tid) {
  const int LOG = 9 - 3 * S;
  const int sub = 1 << LOG;
#pragma unroll
  for (int gi = 0; gi < 2; ++gi) {
    const int g = tid + 256 * gi;
    const int b_hi = g >> LOG;
    const int b_lo = g & (sub - 1);
    const int base = b_hi * (sub << 3) + b_lo;
    int idx[8];
    float ar[8], ai[8];
#pragma unroll
    for (int q = 0; q < 8; ++q) {
      idx[q] = PHYS(base + q * sub);
      ar[q] = SRe[idx[q]];
      ai[q] = SIm[idx[q]];
    }
    float2 t1[4], t2[2], t3;
#pragma unroll
    for (int q = 0; q < 4; ++q) t1[q] = Wt[(b_lo + q * sub) << (3 * S)];
    t2[0] = Wt[b_lo << (3 * S + 1)];
    t2[1] = Wt[(b_lo + sub) << (3 * S + 1)];
    t3 = Wt[b_lo << (3 * S + 2)];
    if (!INV) {
#pragma unroll
      for (int q = 0; q < 4; ++q) {
        float ur = ar[q] - ar[q + 4], ui = ai[q] - ai[q + 4];
        ar[q] += ar[q + 4]; ai[q] += ai[q + 4];
        ar[q + 4] = ur * t1[q].x - ui * t1[q].y;
        ai[q + 4] = ur * t1[q].y + ui * t1[q].x;
      }
#pragma unroll
      for (int h = 0; h < 8; h += 4)
#pragma unroll
        for (int qq = 0; qq < 2; ++qq) {
          int q = h + qq;
          float ur = ar[q] - ar[q + 2], ui = ai[q] - ai[q + 2];
          ar[q] += ar[q + 2]; ai[q] += ai[q + 2];
          ar[q + 2] = ur * t2[qq].x - ui * t2[qq].y;
          ai[q + 2] = ur * t2[qq].y + ui * t2[qq].x;
        }
#pragma unroll
      for (int q = 0; q < 8; q += 2) {
        float ur = ar[q] - ar[q + 1], ui = ai[q] - ai[q + 1];
        ar[q] += ar[q + 1]; ai[q] += ai[q + 1];
        ar[q + 1] = ur * t3.x - ui * t3.y;
        ai[q + 1] = ur * t3.y + ui * t3.x;
      }
    } else {
#pragma unroll
      for (int q = 0; q < 8; q += 2) {
        float br = ar[q + 1] * t3.x + ai[q + 1] * t3.y;
        float bi = ai[q + 1] * t3.x - ar[q + 1] * t3.y;
        ar[q + 1] = ar[q] - br; ai[q + 1] = ai[q] - bi;
        ar[q] += br; ai[q] += bi;
      }
#pragma unroll
      for (int h = 0; h < 8; h += 4)
#pragma unroll
        for (int qq = 0; qq < 2; ++qq) {
          int q = h + qq;
          float br = ar[q + 2] * t2[qq].x + ai[q + 2] * t2[qq].y;
          float bi = ai[q + 2] * t2[qq].x - ar[q + 2] * t2[qq].y;
          ar[q + 2] = ar[q] - br; ai[q + 2] = ai[q] - bi;
          ar[q] += br; ai[q] += bi;
        }
#pragma unroll
      for (int q = 0; q < 4; ++q) {
        float br = ar[q + 4] * t1[q].x + ai[q + 4] * t1[q].y;
        float bi = ai[q + 4] * t1[q].x - ar[q + 4] * t1[q].y;
        ar[q + 4] = ar[q] - br; ai[q + 4] = ai[q] - bi;
        ar[q] += br; ai[q] += bi;
      }
    }
#pragma unroll
    for (int q = 0; q < 8; ++q) { SRe[idx[q]] = ar[q]; SIm[idx[q]] = ai[q]; }
  }
}

__device__ __forceinline__ void s3_fwd(float* ar, float* ai, const float2* __restrict__ Wt) {
  float2 t1[4];
#pragma unroll
  for (int q = 0; q < 4; ++q) t1[q] = Wt[q << 9];
  float2 t20 = Wt[0], t21 = Wt[1 << 10];
#pragma unroll
  for (int q = 0; q < 4; ++q) {
    float ur = ar[q] - ar[q + 4], ui = ai[q] - ai[q + 4];
    ar[q] += ar[q + 4]; ai[q] += ai[q + 4];
    ar[q + 4] = ur * t1[q].x - ui * t1[q].y;
    ai[q + 4] = ur * t1[q].y + ui * t1[q].x;
  }
#pragma unroll
  for (int h = 0; h < 8; h += 4)
#pragma unroll
    for (int qq = 0; qq < 2; ++qq) {
      int q = h + qq;
      float2 t = qq ? t21 : t20;
      float ur = ar[q] - ar[q + 2], ui = ai[q] - ai[q + 2];
      ar[q] += ar[q + 2]; ai[q] += ai[q + 2];
      ar[q + 2] = ur * t.x - ui * t.y;
      ai[q + 2] = ur * t.y + ui * t.x;
    }
#pragma unroll
  for (int q = 0; q < 8; q += 2) {
    float ur = ar[q] - ar[q + 1], ui = ai[q] - ai[q + 1];
    ar[q] += ar[q + 1]; ai[q] += ai[q + 1];
    ar[q + 1] = ur; ai[q + 1] = ui;
  }
}

__device__ __forceinline__ void s3_inv(float* ar, float* ai, const float2* __restrict__ Wt) {
  float2 t1[4];
#pragma unroll
  for (int q = 0; q < 4; ++q) t1[q] = Wt[q << 9];
  float2 t20 = Wt[0], t21 = Wt[1 << 10];
#pragma unroll
  for (int q = 0; q < 8; q += 2) {
    float br = ar[q + 1], bi = ai[q + 1];
    ar[q + 1] = ar[q] - br; ai[q + 1] = ai[q] - bi;
    ar[q] += br; ai[q] += bi;
  }
#pragma unroll
  for (int h = 0; h < 8; h += 4)
#pragma unroll
    for (int qq = 0; qq < 2; ++qq) {
      int q = h + qq;
      float2 t = qq ? t21 : t20;
      float br = ar[q + 2] * t.x + ai[q + 2] * t.y;
      float bi = ai[q + 2] * t.x - ar[q + 2] * t.y;
      ar[q + 2] = ar[q] - br; ai[q + 2] = ai[q] - bi;
      ar[q] += br; ai[q] += bi;
    }
#pragma unroll
  for (int q = 0; q < 4; ++q) {
    float br = ar[q + 4] * t1[q].x + ai[q + 4] * t1[q].y;
    float bi = ai[q + 4] * t1[q].x - ar[q + 4] * t1[q].y;
    ar[q + 4] = ar[q] - br; ai[q + 4] = ai[q] - bi;
    ar[q] += br; ai[q] += bi;
  }
}

__device__ __forceinline__ void corr_write(float* o, const float* st, int j) {
  const int k = (int)((440700928u >> (3 * j)) & 7u);
  const int l = (int)((611428561u >> (3 * j)) & 7u);
  const float Sk = st[k], Sl = st[l];
  const int offk = (k * (11 - k)) >> 1;
  const int offl = (l * (11 - l)) >> 1;
  const float Skl = st[5 + offk + (l - k)];
  const float Skk = st[5 + offk];
  const float Sll = st[5 + offl];
  const float invT = 1.0f / 4096.0f;
  float cov = Skl - Sk * Sl * invT;
  float vk = Skk - Sk * Sk * invT;
  float vl = Sll - Sl * Sl * invT;
  float dk = sqrtf(fmaxf(vk, 0.f)), dl = sqrtf(fmaxf(vl, 0.f));
  float den = dk * dl;
  float corr = den > 0.f ? cov / den : 0.f;
  o[36 + j] = fminf(1.f, fmaxf(-1.f, corr));
}

// ---------------- the one main kernel ----------------
// LDS = 54272 B; 3 blocks/CU target via launch_bounds(256,3) -> ~168 reg cap.
__global__ void __launch_bounds__(NTH, 3)
tf_main(const float* __restrict__ x,
        const float2* __restrict__ Wt,
        const float* __restrict__ Mdr,
        float* __restrict__ out) {
  __shared__ float SRe[4352];
  __shared__ float SIm[4352];
  __shared__ unsigned char hist[NTH * 76];

  const int tid = threadIdx.x;
  const int beta = blockIdx.x;
  // XCD-affinity swizzle: with round-robin dispatch (XCD = blockIdx % 8),
  // all 32 blocks of batch b land on XCD b%8 -> per-XCD set = 2 MB <= L2.
  const int b = (beta & 7) + ((beta >> 8) << 3);
  const int dA = ((beta >> 3) & 31) * 2;

  {  // zero own hist slice
    unsigned int* hw = (unsigned int*)(hist + tid * 76);
#pragma unroll
    for (int i = 0; i < 19; ++i) hw[i] = 0u;
  }

  // ---- stage x directly (two series -> complex); stride-256B float2 loads,
  //      line reuse served by the local XCD L2 thanks to the swizzle ----
  {
    const float2* xp = (const float2*)(x + (size_t)b * 4096 * 64 + dA);
    for (int t = tid; t < 4096; t += NTH) {
      float2 v = xp[(size_t)t * 32];
      SRe[PHYS(t)] = v.x;
      SIm[PHYS(t)] = v.y;
    }
  }
  __syncthreads();

  // ---- forward FFT: stages s=0..2 in LDS, s=3 in regs ----
  fft_stage<0, false>(SRe, SIm, Wt, tid); __syncthreads();
  fft_stage<1, false>(SRe, SIm, Wt, tid); __syncthreads();
  fft_stage<2, false>(SRe, SIm, Wt, tid); __syncthreads();

  float Fr[16], Fi[16];
#pragma unroll
  for (int j = 0; j < 16; ++j) {
    int p = PHYS(tid * 16 + j);
    Fr[j] = SRe[p]; Fi[j] = SIm[p];
  }
  s3_fwd(&Fr[0], &Fi[0], Wt);
  s3_fwd(&Fr[8], &Fi[8], Wt);
  // bitrev12(1)=2048 -> F_Ny = lane0 slot1; park in PHYS hole slot 16
  // (PHYS(i)=i+(i>>4) never maps to slots ==16 mod 17, so it survives)
  if (tid == 0) { SRe[16] = Fr[1]; SIm[16] = Fi[1]; }

  // retained f16 modes of bands 0,1 (32 VGPRs) + moment accumulators
  f16x2 rA0[8], rB0[8], rA1[8], rB1[8];
  float d4a = 0.f, d4b = 0.f;
  float accA[20], accB[20];

#pragma unroll
  for (int k = 0; k < 3; ++k) {
    __syncthreads();  // previous band's readers done; also publishes fny
#pragma unroll
    for (int h = 0; h < 2; ++h) {
      float Zr[8], Zi[8];
#pragma unroll
      for (int j = 0; j < 8; ++j) {
        float m = Mdr[k * 4096 + tid * 16 + h * 8 + j];
        Zr[j] = Fr[h * 8 + j] * m; Zi[j] = Fi[h * 8 + j] * m;
      }
      s3_inv(Zr, Zi, Wt);
#pragma unroll
      for (int j = 0; j < 8; ++j) {
        int p = PHYS(tid * 16 + h * 8 + j);
        SRe[p] = Zr[j]; SIm[p] = Zi[j];
      }
    }
    __syncthreads();
    fft_stage<2, true>(SRe, SIm, Wt, tid); __syncthreads();
    fft_stage<1, true>(SRe, SIm, Wt, tid); __syncthreads();
    fft_stage<0, true>(SRe, SIm, Wt, tid); __syncthreads();
    // SRe[t] = modes_a[t] (band k), SIm[t] = modes_b[t], natural order

    // ---- band pass ----
    {
      const int t0 = tid * 16;
      float a0 = SRe[PHYS(t0)], a1 = SRe[PHYS(t0 + 1)];
      float c0 = SIm[PHYS(t0)], c1 = SIm[PHYS(t0 + 1)];
      int pa = 0, pb = 0;
      unsigned char* myh = hist + tid * 76;

      // mirror-band Nyquist correction constants
      float da = 0.f, db = 0.f;
      float aq0 = 0.f, aq1 = 0.f, cq0 = 0.f, cq1 = 0.f;
      int pa2 = 0, pb2 = 0;
      if (k >= 1) {
        float m_mir = mask_f32(5 - k, 2048);   // k=1 -> band4, k=2 -> band3
        float m_own = mask_f32(k, 2048);
        float dM = (float)(((double)m_mir - (double)m_own) * (1.0 / 4096.0));
        da = dM * SRe[16];
        db = dM * SIm[16];
        aq0 = a0 + da; aq1 = a1 - da;      // t0 even -> sigma=+1 at t0
        cq0 = c0 + db; cq1 = c1 - db;
      }
      if (k == 1) { d4a = da; d4b = db; }

      // prologue j = 0,1
      if (k == 0) {
        rset(rA0, 0, a0); rset(rA0, 1, a1);
        rset(rB0, 0, c0); rset(rB0, 1, c1);
      } else if (k == 1) {
        rset(rA1, 0, a0); rset(rA1, 1, a1);
        rset(rB1, 0, c0); rset(rB1, 1, c1);
      } else {
#pragma unroll
        for (int j = 0; j < 20; ++j) { accA[j] = 0.f; accB[j] = 0.f; }
        madd5(accA, rget(rA0, 0), rget(rA1, 0), a0, a0 + da, rget(rA1, 0) + d4a);
        madd5(accB, rget(rB0, 0), rget(rB1, 0), c0, c0 + db, rget(rB1, 0) + d4b);
        madd5(accA, rget(rA0, 1), rget(rA1, 1), a1, a1 - da, rget(rA1, 1) - d4a);
        madd5(accB, rget(rB0, 1), rget(rB1, 1), c1, c1 - db, rget(rB1, 1) - d4b);
      }

#pragma unroll
      for (int step = 0; step <= 16; ++step) {
        const int w = t0 + step;
        if (w < 4094) {
          float a2 = SRe[PHYS(w + 2)];
          float c2 = SIm[PHYS(w + 2)];
          const float sg = (step & 1) ? -1.f : 1.f;   // sigma at t = t0+step+2 (t0 even)
          if (step <= 13) {
            const int j = step + 2;                   // parity of j == parity of step
            if (k == 0) {
              rset(rA0, j, a2); rset(rB0, j, c2);
            } else if (k == 1) {
              rset(rA1, j, a2); rset(rB1, j, c2);
            } else {
              madd5(accA, rget(rA0, j), rget(rA1, j), a2, a2 + sg * da, rget(rA1, j) + sg * d4a);
              madd5(accB, rget(rB0, j), rget(rB1, j), c2, c2 + sg * db, rget(rB1, j) + sg * d4b);
            }
          }
          int ia = (int)(a0 <= a1) | ((int)(a0 <= a2) << 1) | ((int)(a1 <= a2) << 2);
          int ca = (int)((537125u >> (3 * ia)) & 7u);
          int ib = (int)(c0 <= c1) | ((int)(c0 <= c2) << 1) | ((int)(c1 <= c2) << 2);
          int cb = (int)((537125u >> (3 * ib)) & 7u);
          if (step >= 1) { myh[pa * 6 + ca] += 1; myh[36 + pb * 6 + cb] += 1; }
          pa = ca; pb = cb;
          a0 = a1; a1 = a2;
          c0 = c1; c1 = c2;

          if (k >= 1) {
            const float sda = sg * da;
            const float sdb = sg * db;
            float aq2 = a2 + sda;
            float cq2 = c2 + sdb;
            int ia2 = (int)(aq0 <= aq1) | ((int)(aq0 <= aq2) << 1) | ((int)(aq1 <= aq2) << 2);
            int ca2 = (int)((537125u >> (3 * ia2)) & 7u);
            int ib2 = (int)(cq0 <= cq1) | ((int)(cq0 <= cq2) << 1) | ((int)(cq1 <= cq2) << 2);
            int cb2 = (int)((537125u >> (3 * ib2)) & 7u);
            if (step >= 1) { myh[pa2 * 6 + ca2] += 1; myh[36 + pb2 * 6 + cb2] += 1; }
            pa2 = ca2; pb2 = cb2;
            aq0 = aq1; aq1 = aq2;
            cq0 = cq1; cq1 = cq2;
          }
        }
      }
    }
  }
  __syncthreads();   // all band-pass LDS reads done -> SRe/SIm reusable

  // epilogue scratch overlaid on FFT buffers
  float* red = SIm;                          // [4][40]
  float* stats = SIm + 160;                  // 40
  float* rowinv = SIm + 200;                 // 12
  unsigned int* histf = (unsigned int*)SRe;  // 72

  // ---- 40-way moment block reduce ----
  const int lane = tid & 63, wv = tid >> 6;
#pragma unroll
  for (int j = 0; j < 40; ++j) {
    float v = (j < 20) ? accA[j] : accB[j - 20];
    v += __shfl_down(v, 32, 64);
    v += __shfl_down(v, 16, 64);
    v += __shfl_down(v, 8, 64);
    v += __shfl_down(v, 4, 64);
    v += __shfl_down(v, 2, 64);
    v += __shfl_down(v, 1, 64);
    if (lane == 0) red[wv * 40 + j] = v;
  }
  __syncthreads();
  if (tid < 40) stats[tid] = red[tid] + red[40 + tid] + red[80 + tid] + red[120 + tid];
  if (tid < 72) {
    unsigned int s = 0;
    for (int i = 0; i < 256; ++i) s += (unsigned int)hist[i * 76 + tid];
    histf[tid] = s;
  }
  __syncthreads();
  if (tid < 12) {
    int base0 = (tid < 6 ? 0 : 36) + (tid % 6) * 6;
    float rs = (float)(histf[base0] + histf[base0 + 1] + histf[base0 + 2] +
                       histf[base0 + 3] + histf[base0 + 4] + histf[base0 + 5]);
    rowinv[tid] = rs > 0.f ? 1.0f / rs : 1.0f;
  }
  __syncthreads();

  float* oA = out + (size_t)(b * 64 + dA) * 46;
  float* oB = oA + 46;
  if (tid < 36) oA[tid] = (float)histf[tid] * rowinv[tid / 6];
  if (tid >= 64 && tid < 100) {
    int j = tid - 64;
    oB[j] = (float)histf[36 + j] * rowinv[6 + j / 6];
  }
  if (tid >= 128 && tid < 138) corr_write(oA, stats, tid - 128);
  if (tid >= 160 && tid < 170) corr_write(oB, stats + 20, tid - 160);
}

// ---------------- launch ----------------
extern "C" void kernel_launch(void* const* d_in, const int* in_sizes, int n_in,
                              void* d_out, int out_size, void* d_ws, size_t ws_size,
                              hipStream_t stream) {
  (void)in_sizes; (void)n_in; (void)out_size; (void)ws_size;
  const float* x = (const float*)d_in[0];
  float* out = (float*)d_out;
  char* ws = (char*)d_ws;

  float2* Wt = (float2*)ws;                      // 32 KB
  float* Mdr = (float*)(ws + 32768);             // 48 KB (3 bands)

  setup_k<<<16, NTH, 0, stream>>>(Wt, Mdr);
  tf_main<<<512, NTH, 0, stream>>>(x, Wt, Mdr, out);
}

// Round 15
// 117.920 us; speedup vs baseline: 1.2583x; 1.2583x over previous
//
#include <hip/hip_runtime.h>
#include <math.h>

// Best-known assembly of all proven pieces (r14's (256,3) spilled: 4th
// confirmation that any cap except (256,2)'s 256-total/wave makes the
// allocator choose-low-and-spill; 2 blocks/CU is this structure's ceiling).
//   - r11 transpose staging: setup_k transposes x -> xT; tf_main stages via
//     4 coalesced float4 loads/thread (10 us faster than direct strided).
//   - r12/r13 fny-in-PHYS-hole: LDS 54272 B.
//   - launch_bounds(256,2): the only spill-free 2-blocks/CU config.
//   - XCD swizzle kept (no-op for xT path, protects the no-ws fallback).

#define NTH 256
#define PHYS(i) ((i) + ((i) >> 4))

typedef _Float16 f16x2 __attribute__((ext_vector_type(2)));

__device__ __forceinline__ void rset(f16x2* r, int j, float v) {
  if (j & 1) r[j >> 1].y = (_Float16)v;
  else       r[j >> 1].x = (_Float16)v;
}
__device__ __forceinline__ float rget(const f16x2* r, int j) {
  return (j & 1) ? (float)r[j >> 1].y : (float)r[j >> 1].x;
}

// accumulate 5 band energies + upper-triangular products into acc[20]
__device__ __forceinline__ void madd5(float* acc, float m0, float m1, float m2,
                                      float m3, float m4) {
  float e[5];
  e[0] = m0 * m0; e[1] = m1 * m1; e[2] = m2 * m2; e[3] = m3 * m3; e[4] = m4 * m4;
  int id = 5;
#pragma unroll
  for (int a = 0; a < 5; ++a) {
    acc[a] += e[a];
#pragma unroll
    for (int l = a; l < 5; ++l) { acc[id] += e[a] * e[l]; ++id; }
  }
}

// ---------------- fused setup: transpose + tables ----------------
__device__ __forceinline__ float mask_f32(int k, int j) {
  // replicate reference: freqs=fftfreq(4096).astype(f32), centers f32, /0.2f, expf
  float f = (float)((j < 2048) ? j : (j - 4096)) * (1.0f / 4096.0f);
  float c = ((float)k - 2.5f) / 5.0f;
  float df = fabsf(f - c);
  float q = df / 0.2f;
  return expf(-0.5f * (q * q));
}

__global__ void setup_k(const float* __restrict__ x, float* __restrict__ xT,
                        float2* __restrict__ Wt, float* __restrict__ Mdr, int n_trans) {
  __shared__ float tile[64][65];
  if ((int)blockIdx.x < n_trans) {
    int bb = blockIdx.x >> 6;
    int tt = blockIdx.x & 63;
    int lane = threadIdx.x & 63;
    int grp = threadIdx.x >> 6;
#pragma unroll
    for (int r = 0; r < 16; ++r) {
      int tl = grp + 4 * r;
      tile[tl][lane] = x[((size_t)bb * 4096 + tt * 64 + tl) * 64 + lane];
    }
    __syncthreads();
#pragma unroll
    for (int r = 0; r < 16; ++r) {
      int dl = grp + 4 * r;
      xT[((size_t)bb * 64 + dl) * 4096 + tt * 64 + lane] = tile[lane][dl];
    }
  } else {
    int j = (blockIdx.x - n_trans) * NTH + threadIdx.x;   // 0..4095
    double ang = -(2.0 * 3.14159265358979323846 / 4096.0) * (double)j;
    double s, c;
    sincos(ang, &s, &c);
    Wt[j] = make_float2((float)c, (float)s);
    int jr = (int)(__brev((unsigned)j) >> 20);            // bitrev12
    int jrn = (4096 - jr) & 4095;
#pragma unroll
    for (int k = 0; k < 3; ++k) {   // bands 0,1,2; 3,4 via Nyquist correction
      float m1 = mask_f32(k, jr);
      float m2 = mask_f32(k, jrn);
      Mdr[k * 4096 + j] = (float)(((double)m1 + (double)m2) * (0.5 / 4096.0));
    }
  }
}

// ---------------- FFT building blocks (f32) ----------------
template <int S, bool INV>
__device__ __forceinline__ void fft_stage(float* __restrict__ SRe, float* __restrict__ SIm,
                                          const float2* __restrict__ Wt, int tid) {
  const int LOG = 9 - 3 * S;
  const int sub = 1 << LOG;
#pragma unroll
  for (int gi = 0; gi < 2; ++gi) {
    const int g = tid + 256 * gi;
    const int b_hi = g >> LOG;
    const int b_lo = g & (sub - 1);
    const int base = b_hi * (sub << 3) + b_lo;
    int idx[8];
    float ar[8], ai[8];
#pragma unroll
    for (int q = 0; q < 8; ++q) {
      idx[q] = PHYS(base + q * sub);
      ar[q] = SRe[idx[q]];
      ai[q] = SIm[idx[q]];
    }
    float2 t1[4], t2[2], t3;
#pragma unroll
    for (int q = 0; q < 4; ++q) t1[q] = Wt[(b_lo + q * sub) << (3 * S)];
    t2[0] = Wt[b_lo << (3 * S + 1)];
    t2[1] = Wt[(b_lo + sub) << (3 * S + 1)];
    t3 = Wt[b_lo << (3 * S + 2)];
    if (!INV) {
#pragma unroll
      for (int q = 0; q < 4; ++q) {
        float ur = ar[q] - ar[q + 4], ui = ai[q] - ai[q + 4];
        ar[q] += ar[q + 4]; ai[q] += ai[q + 4];
        ar[q + 4] = ur * t1[q].x - ui * t1[q].y;
        ai[q + 4] = ur * t1[q].y + ui * t1[q].x;
      }
#pragma unroll
      for (int h = 0; h < 8; h += 4)
#pragma unroll
        for (int qq = 0; qq < 2; ++qq) {
          int q = h + qq;
          float ur = ar[q] - ar[q + 2], ui = ai[q] - ai[q + 2];
          ar[q] += ar[q + 2]; ai[q] += ai[q + 2];
          ar[q + 2] = ur * t2[qq].x - ui * t2[qq].y;
          ai[q + 2] = ur * t2[qq].y + ui * t2[qq].x;
        }
#pragma unroll
      for (int q = 0; q < 8; q += 2) {
        float ur = ar[q] - ar[q + 1], ui = ai[q] - ai[q + 1];
        ar[q] += ar[q + 1]; ai[q] += ai[q + 1];
        ar[q + 1] = ur * t3.x - ui * t3.y;
        ai[q + 1] = ur * t3.y + ui * t3.x;
      }
    } else {
#pragma unroll
      for (int q = 0; q < 8; q += 2) {
        float br = ar[q + 1] * t3.x + ai[q + 1] * t3.y;
        float bi = ai[q + 1] * t3.x - ar[q + 1] * t3.y;
        ar[q + 1] = ar[q] - br; ai[q + 1] = ai[q] - bi;
        ar[q] += br; ai[q] += bi;
      }
#pragma unroll
      for (int h = 0; h < 8; h += 4)
#pragma unroll
        for (int qq = 0; qq < 2; ++qq) {
          int q = h + qq;
          float br = ar[q + 2] * t2[qq].x + ai[q + 2] * t2[qq].y;
          float bi = ai[q + 2] * t2[qq].x - ar[q + 2] * t2[qq].y;
          ar[q + 2] = ar[q] - br; ai[q + 2] = ai[q] - bi;
          ar[q] += br; ai[q] += bi;
        }
#pragma unroll
      for (int q = 0; q < 4; ++q) {
        float br = ar[q + 4] * t1[q].x + ai[q + 4] * t1[q].y;
        float bi = ai[q + 4] * t1[q].x - ar[q + 4] * t1[q].y;
        ar[q + 4] = ar[q] - br; ai[q + 4] = ai[q] - bi;
        ar[q] += br; ai[q] += bi;
      }
    }
#pragma unroll
    for (int q = 0; q < 8; ++q) { SRe[idx[q]] = ar[q]; SIm[idx[q]] = ai[q]; }
  }
}

__device__ __forceinline__ void s3_fwd(float* ar, float* ai, const float2* __restrict__ Wt) {
  float2 t1[4];
#pragma unroll
  for (int q = 0; q < 4; ++q) t1[q] = Wt[q << 9];
  float2 t20 = Wt[0], t21 = Wt[1 << 10];
#pragma unroll
  for (int q = 0; q < 4; ++q) {
    float ur = ar[q] - ar[q + 4], ui = ai[q] - ai[q + 4];
    ar[q] += ar[q + 4]; ai[q] += ai[q + 4];
    ar[q + 4] = ur * t1[q].x - ui * t1[q].y;
    ai[q + 4] = ur * t1[q].y + ui * t1[q].x;
  }
#pragma unroll
  for (int h = 0; h < 8; h += 4)
#pragma unroll
    for (int qq = 0; qq < 2; ++qq) {
      int q = h + qq;
      float2 t = qq ? t21 : t20;
      float ur = ar[q] - ar[q + 2], ui = ai[q] - ai[q + 2];
      ar[q] += ar[q + 2]; ai[q] += ai[q + 2];
      ar[q + 2] = ur * t.x - ui * t.y;
      ai[q + 2] = ur * t.y + ui * t.x;
    }
#pragma unroll
  for (int q = 0; q < 8; q += 2) {
    float ur = ar[q] - ar[q + 1], ui = ai[q] - ai[q + 1];
    ar[q] += ar[q + 1]; ai[q] += ai[q + 1];
    ar[q + 1] = ur; ai[q + 1] = ui;
  }
}

__device__ __forceinline__ void s3_inv(float* ar, float* ai, const float2* __restrict__ Wt) {
  float2 t1[4];
#pragma unroll
  for (int q = 0; q < 4; ++q) t1[q] = Wt[q << 9];
  float2 t20 = Wt[0], t21 = Wt[1 << 10];
#pragma unroll
  for (int q = 0; q < 8; q += 2) {
    float br = ar[q + 1], bi = ai[q + 1];
    ar[q + 1] = ar[q] - br; ai[q + 1] = ai[q] - bi;
    ar[q] += br; ai[q] += bi;
  }
#pragma unroll
  for (int h = 0; h < 8; h += 4)
#pragma unroll
    for (int qq = 0; qq < 2; ++qq) {
      int q = h + qq;
      float2 t = qq ? t21 : t20;
      float br = ar[q + 2] * t.x + ai[q + 2] * t.y;
      float bi = ai[q + 2] * t.x - ar[q + 2] * t.y;
      ar[q + 2] = ar[q] - br; ai[q + 2] = ai[q] - bi;
      ar[q] += br; ai[q] += bi;
    }
#pragma unroll
  for (int q = 0; q < 4; ++q) {
    float br = ar[q + 4] * t1[q].x + ai[q + 4] * t1[q].y;
    float bi = ai[q + 4] * t1[q].x - ar[q + 4] * t1[q].y;
    ar[q + 4] = ar[q] - br; ai[q + 4] = ai[q] - bi;
    ar[q] += br; ai[q] += bi;
  }
}

__device__ __forceinline__ void corr_write(float* o, const float* st, int j) {
  const int k = (int)((440700928u >> (3 * j)) & 7u);
  const int l = (int)((611428561u >> (3 * j)) & 7u);
  const float Sk = st[k], Sl = st[l];
  const int offk = (k * (11 - k)) >> 1;
  const int offl = (l * (11 - l)) >> 1;
  const float Skl = st[5 + offk + (l - k)];
  const float Skk = st[5 + offk];
  const float Sll = st[5 + offl];
  const float invT = 1.0f / 4096.0f;
  float cov = Skl - Sk * Sl * invT;
  float vk = Skk - Sk * Sk * invT;
  float vl = Sll - Sl * Sl * invT;
  float dk = sqrtf(fmaxf(vk, 0.f)), dl = sqrtf(fmaxf(vl, 0.f));
  float den = dk * dl;
  float corr = den > 0.f ? cov / den : 0.f;
  o[36 + j] = fminf(1.f, fmaxf(-1.f, corr));
}

// ---------------- the one main kernel ----------------
// LDS = 54272 B (fny parked in PHYS holes SRe/SIm[16]); (256,2) -> 2 blocks/CU.
__global__ void __launch_bounds__(NTH, 2)
tf_main(const float* __restrict__ x,
        const float* __restrict__ xT, int use_xt,
        const float2* __restrict__ Wt,
        const float* __restrict__ Mdr,
        float* __restrict__ out) {
  __shared__ float SRe[4352];
  __shared__ float SIm[4352];
  __shared__ unsigned char hist[NTH * 76];

  const int tid = threadIdx.x;
  const int beta = blockIdx.x;
  // XCD-affinity swizzle (r13-verified): no-op for xT path, keeps the no-ws
  // fallback L2-local (round-robin dispatch XCD = blockIdx % 8).
  const int b = (beta & 7) + ((beta >> 8) << 3);
  const int dA = ((beta >> 3) & 31) * 2;

  {  // zero own hist slice
    unsigned int* hw = (unsigned int*)(hist + tid * 76);
#pragma unroll
    for (int i = 0; i < 19; ++i) hw[i] = 0u;
  }

  // ---- stage x (two series -> complex) ----
  if (use_xt) {
    const float4* ra = (const float4*)(xT + (size_t)(b * 64 + dA) * 4096);
    const float4* rb = (const float4*)(xT + (size_t)(b * 64 + dA + 1) * 4096);
    for (int t4 = tid; t4 < 1024; t4 += NTH) {
      float4 va = ra[t4], vb = rb[t4];
      int t = t4 * 4;
      SRe[PHYS(t)] = va.x;     SIm[PHYS(t)] = vb.x;
      SRe[PHYS(t + 1)] = va.y; SIm[PHYS(t + 1)] = vb.y;
      SRe[PHYS(t + 2)] = va.z; SIm[PHYS(t + 2)] = vb.z;
      SRe[PHYS(t + 3)] = va.w; SIm[PHYS(t + 3)] = vb.w;
    }
  } else {
    const float2* xp = (const float2*)(x + (size_t)b * 4096 * 64 + dA);
    for (int t = tid; t < 4096; t += NTH) {
      float2 v = xp[(size_t)t * 32];
      SRe[PHYS(t)] = v.x;
      SIm[PHYS(t)] = v.y;
    }
  }
  __syncthreads();

  // ---- forward FFT: stages s=0..2 in LDS, s=3 in regs ----
  fft_stage<0, false>(SRe, SIm, Wt, tid); __syncthreads();
  fft_stage<1, false>(SRe, SIm, Wt, tid); __syncthreads();
  fft_stage<2, false>(SRe, SIm, Wt, tid); __syncthreads();

  float Fr[16], Fi[16];
#pragma unroll
  for (int j = 0; j < 16; ++j) {
    int p = PHYS(tid * 16 + j);
    Fr[j] = SRe[p]; Fi[j] = SIm[p];
  }
  s3_fwd(&Fr[0], &Fi[0], Wt);
  s3_fwd(&Fr[8], &Fi[8], Wt);
  // bitrev12(1)=2048 -> F_Ny = lane0 slot1; park in PHYS hole slot 16
  // (PHYS(i)=i+(i>>4) never maps to slots ==16 mod 17, so it survives)
  if (tid == 0) { SRe[16] = Fr[1]; SIm[16] = Fi[1]; }

  // retained f16 modes of bands 0,1 (32 VGPRs) + moment accumulators
  f16x2 rA0[8], rB0[8], rA1[8], rB1[8];
  float d4a = 0.f, d4b = 0.f;
  float accA[20], accB[20];

#pragma unroll
  for (int k = 0; k < 3; ++k) {
    __syncthreads();  // previous band's readers done; also publishes fny
#pragma unroll
    for (int h = 0; h < 2; ++h) {
      float Zr[8], Zi[8];
#pragma unroll
      for (int j = 0; j < 8; ++j) {
        float m = Mdr[k * 4096 + tid * 16 + h * 8 + j];
        Zr[j] = Fr[h * 8 + j] * m; Zi[j] = Fi[h * 8 + j] * m;
      }
      s3_inv(Zr, Zi, Wt);
#pragma unroll
      for (int j = 0; j < 8; ++j) {
        int p = PHYS(tid * 16 + h * 8 + j);
        SRe[p] = Zr[j]; SIm[p] = Zi[j];
      }
    }
    __syncthreads();
    fft_stage<2, true>(SRe, SIm, Wt, tid); __syncthreads();
    fft_stage<1, true>(SRe, SIm, Wt, tid); __syncthreads();
    fft_stage<0, true>(SRe, SIm, Wt, tid); __syncthreads();
    // SRe[t] = modes_a[t] (band k), SIm[t] = modes_b[t], natural order

    // ---- band pass ----
    {
      const int t0 = tid * 16;
      float a0 = SRe[PHYS(t0)], a1 = SRe[PHYS(t0 + 1)];
      float c0 = SIm[PHYS(t0)], c1 = SIm[PHYS(t0 + 1)];
      int pa = 0, pb = 0;
      unsigned char* myh = hist + tid * 76;

      // mirror-band Nyquist correction constants
      float da = 0.f, db = 0.f;
      float aq0 = 0.f, aq1 = 0.f, cq0 = 0.f, cq1 = 0.f;
      int pa2 = 0, pb2 = 0;
      if (k >= 1) {
        float m_mir = mask_f32(5 - k, 2048);   // k=1 -> band4, k=2 -> band3
        float m_own = mask_f32(k, 2048);
        float dM = (float)(((double)m_mir - (double)m_own) * (1.0 / 4096.0));
        da = dM * SRe[16];
        db = dM * SIm[16];
        aq0 = a0 + da; aq1 = a1 - da;      // t0 even -> sigma=+1 at t0
        cq0 = c0 + db; cq1 = c1 - db;
      }
      if (k == 1) { d4a = da; d4b = db; }

      // prologue j = 0,1
      if (k == 0) {
        rset(rA0, 0, a0); rset(rA0, 1, a1);
        rset(rB0, 0, c0); rset(rB0, 1, c1);
      } else if (k == 1) {
        rset(rA1, 0, a0); rset(rA1, 1, a1);
        rset(rB1, 0, c0); rset(rB1, 1, c1);
      } else {
#pragma unroll
        for (int j = 0; j < 20; ++j) { accA[j] = 0.f; accB[j] = 0.f; }
        madd5(accA, rget(rA0, 0), rget(rA1, 0), a0, a0 + da, rget(rA1, 0) + d4a);
        madd5(accB, rget(rB0, 0), rget(rB1, 0), c0, c0 + db, rget(rB1, 0) + d4b);
        madd5(accA, rget(rA0, 1), rget(rA1, 1), a1, a1 - da, rget(rA1, 1) - d4a);
        madd5(accB, rget(rB0, 1), rget(rB1, 1), c1, c1 - db, rget(rB1, 1) - d4b);
      }

#pragma unroll
      for (int step = 0; step <= 16; ++step) {
        const int w = t0 + step;
        if (w < 4094) {
          float a2 = SRe[PHYS(w + 2)];
          float c2 = SIm[PHYS(w + 2)];
          const float sg = (step & 1) ? -1.f : 1.f;   // sigma at t = t0+step+2 (t0 even)
          if (step <= 13) {
            const int j = step + 2;                   // parity of j == parity of step
            if (k == 0) {
              rset(rA0, j, a2); rset(rB0, j, c2);
            } else if (k == 1) {
              rset(rA1, j, a2); rset(rB1, j, c2);
            } else {
              madd5(accA, rget(rA0, j), rget(rA1, j), a2, a2 + sg * da, rget(rA1, j) + sg * d4a);
              madd5(accB, rget(rB0, j), rget(rB1, j), c2, c2 + sg * db, rget(rB1, j) + sg * d4b);
            }
          }
          int ia = (int)(a0 <= a1) | ((int)(a0 <= a2) << 1) | ((int)(a1 <= a2) << 2);
          int ca = (int)((537125u >> (3 * ia)) & 7u);
          int ib = (int)(c0 <= c1) | ((int)(c0 <= c2) << 1) | ((int)(c1 <= c2) << 2);
          int cb = (int)((537125u >> (3 * ib)) & 7u);
          if (step >= 1) { myh[pa * 6 + ca] += 1; myh[36 + pb * 6 + cb] += 1; }
          pa = ca; pb = cb;
          a0 = a1; a1 = a2;
          c0 = c1; c1 = c2;

          if (k >= 1) {
            const float sda = sg * da;
            const float sdb = sg * db;
            float aq2 = a2 + sda;
            float cq2 = c2 + sdb;
            int ia2 = (int)(aq0 <= aq1) | ((int)(aq0 <= aq2) << 1) | ((int)(aq1 <= aq2) << 2);
            int ca2 = (int)((537125u >> (3 * ia2)) & 7u);
            int ib2 = (int)(cq0 <= cq1) | ((int)(cq0 <= cq2) << 1) | ((int)(cq1 <= cq2) << 2);
            int cb2 = (int)((537125u >> (3 * ib2)) & 7u);
            if (step >= 1) { myh[pa2 * 6 + ca2] += 1; myh[36 + pb2 * 6 + cb2] += 1; }
            pa2 = ca2; pb2 = cb2;
            aq0 = aq1; aq1 = aq2;
            cq0 = cq1; cq1 = cq2;
          }
        }
      }
    }
  }
  __syncthreads();   // all band-pass LDS reads done -> SRe/SIm reusable

  // epilogue scratch overlaid on FFT buffers
  float* red = SIm;                          // [4][40]
  float* stats = SIm + 160;                  // 40
  float* rowinv = SIm + 200;                 // 12
  unsigned int* histf = (unsigned int*)SRe;  // 72

  // ---- 40-way moment block reduce ----
  const int lane = tid & 63, wv = tid >> 6;
#pragma unroll
  for (int j = 0; j < 40; ++j) {
    float v = (j < 20) ? accA[j] : accB[j - 20];
    v += __shfl_down(v, 32, 64);
    v += __shfl_down(v, 16, 64);
    v += __shfl_down(v, 8, 64);
    v += __shfl_down(v, 4, 64);
    v += __shfl_down(v, 2, 64);
    v += __shfl_down(v, 1, 64);
    if (lane == 0) red[wv * 40 + j] = v;
  }
  __syncthreads();
  if (tid < 40) stats[tid] = red[tid] + red[40 + tid] + red[80 + tid] + red[120 + tid];
  if (tid < 72) {
    unsigned int s = 0;
    for (int i = 0; i < 256; ++i) s += (unsigned int)hist[i * 76 + tid];
    histf[tid] = s;
  }
  __syncthreads();
  if (tid < 12) {
    int base0 = (tid < 6 ? 0 : 36) + (tid % 6) * 6;
    float rs = (float)(histf[base0] + histf[base0 + 1] + histf[base0 + 2] +
                       histf[base0 + 3] + histf[base0 + 4] + histf[base0 + 5]);
    rowinv[tid] = rs > 0.f ? 1.0f / rs : 1.0f;
  }
  __syncthreads();

  float* oA = out + (size_t)(b * 64 + dA) * 46;
  float* oB = oA + 46;
  if (tid < 36) oA[tid] = (float)histf[tid] * rowinv[tid / 6];
  if (tid >= 64 && tid < 100) {
    int j = tid - 64;
    oB[j] = (float)histf[36 + j] * rowinv[6 + j / 6];
  }
  if (tid >= 128 && tid < 138) corr_write(oA, stats, tid - 128);
  if (tid >= 160 && tid < 170) corr_write(oB, stats + 20, tid - 160);
}

// ---------------- launch ----------------
extern "C" void kernel_launch(void* const* d_in, const int* in_sizes, int n_in,
                              void* d_out, int out_size, void* d_ws, size_t ws_size,
                              hipStream_t stream) {
  (void)in_sizes; (void)n_in; (void)out_size;
  const float* x = (const float*)d_in[0];
  float* out = (float*)d_out;
  char* ws = (char*)d_ws;

  float2* Wt = (float2*)ws;                      // 32 KB
  float* Mdr = (float*)(ws + 32768);             // 48 KB (3 bands)
  float* xT = (float*)(ws + 131072);             // 16.78 MB (optional)
  int use_xt = (ws_size >= (size_t)131072 + (size_t)16 * 64 * 4096 * 4) ? 1 : 0;
  int n_trans = use_xt ? 1024 : 0;

  setup_k<<<n_trans + 16, NTH, 0, stream>>>(x, xT, Wt, Mdr, n_trans);
  tf_main<<<512, NTH, 0, stream>>>(x, xT, use_xt, Wt, Mdr, out);
}